// Round 5
// baseline (614.640 us; speedup 1.0000x reference)
//
#include <hip/hip_runtime.h>
#include <math.h>

#define PI_F 3.14159265358979323846f

// Problem constants (fixed by reference):
// x:[16][64][256][256] f32, weights ×4:[64][64][32][32] f32, out:[16][64][256][256] f32
// modes: ky m=0..63 -> ky = m (m<32) else m+192 ; kx = 0..31
//
// Fused pipeline (X2/Cc scratch in d_ws; no A1/Y1 HBM round-trips):
//   AB: per bi: A-tile (x-DFT) in LDS halves -> y-contraction -> X2[bi][mode]
//   C : Cc[b*64+o][mode] = sum_i X2 * W (complex), * c_kx/65536   (XCD-chunked)
//   DE: per bo: inverse-y into LDS half -> inverse-x + Re() -> out rows

static constexpr int T_TWXA = 0;        // [256 w][64]   cos | -sin   (fwd x)
static constexpr int T_TWYB = 16384;    // [256 h][128]  cos[64] | sin[64] at ky(m)
static constexpr int T_TWYT = 49152;    // [2][64 m][256 h]  cos plane, sin plane
static constexpr int T_TWXT = 81920;    // [64][256]     rows 0..31 cos, 32..63 sin
static constexpr int T_X2   = 98304;                  // [1024][2048] float2
static constexpr int T_CC   = 98304 + 4194304;        // [1024][2048] float2

// ---------------- twiddle tables ----------------
__global__ __launch_bounds__(256) void k_prep(float* __restrict__ ws) {
  int idx = blockIdx.x * 256 + threadIdx.x;
  if (idx < 16384) {
    int w = idx >> 6, col = idx & 63, k = col & 31;
    float ang = (2.0f * PI_F / 256.0f) * (float)((k * w) & 255);
    ws[T_TWXA + idx] = (col < 32) ? cosf(ang) : -sinf(ang);
  } else if (idx < 49152) {
    int j = idx - 16384;
    int h = j >> 7, col = j & 127, m = col & 63;
    int ky = (m < 32) ? m : (m + 192);
    float ang = (2.0f * PI_F / 256.0f) * (float)((ky * h) & 255);
    ws[idx] = (col < 64) ? cosf(ang) : sinf(ang);
  } else if (idx < 81920) {
    int j = idx - 49152;
    int part = j >> 14, m = (j >> 8) & 63, h = j & 255;
    int ky = (m < 32) ? m : (m + 192);
    float ang = (2.0f * PI_F / 256.0f) * (float)((ky * h) & 255);
    ws[idx] = part ? sinf(ang) : cosf(ang);
  } else if (idx < 98304) {
    int j = idx - 81920;
    int row = j >> 8, w = j & 255, k = row & 31;
    float ang = (2.0f * PI_F / 256.0f) * (float)((k * w) & 255);
    ws[idx] = (row < 32) ? cosf(ang) : sinf(ang);
  }
}

// ---------------- AB: forward x-DFT + y-DFT fused ----------------
// grid 1024 (b*64+i); block 256. Two 128-h halves:
//   A phase: 64x64-tile GEMM (16 cg x 16 rg, 4x4 acc) into As[128][64] LDS,
//            x/tw chunks reg-prefetched one step ahead.
//   B phase: partial h-contraction (conj twiddle) accumulated across halves.
__global__ __launch_bounds__(256, 2) void k_AB(const float* __restrict__ x,
                                               const float* __restrict__ twxA,
                                               const float* __restrict__ twyB,
                                               float2* __restrict__ X2) {
  __shared__ float tws[64][68];   // [k][col]
  __shared__ float xsT[64][68];   // [k][swizzled row]
  __shared__ float As[128][64];   // [h local][col]  (stride 64: writes 2-way-min, reads broadcast)
  const int t = threadIdx.x;
  const int bi = blockIdx.x;
  const int cg = t & 15, rg = t >> 4;
  const int m = t >> 2, kx0 = (t & 3) * 8;
  const float* xp = x + (size_t)bi * 65536;

  float accBr[8] = {0,0,0,0,0,0,0,0};
  float accBi[8] = {0,0,0,0,0,0,0,0};

  for (int half = 0; half < 2; ++half) {
    float4 twr[4], xr[4];
    // cold load: step 0 of this half (ht2=0, kc=0)
    {
      const float4* tsrc = (const float4*)twxA;
      const float* xsrc = xp + (size_t)(half * 128) * 256;
#pragma unroll
      for (int j = 0; j < 4; ++j) {
        int f4 = t + 256 * j;
        twr[j] = tsrc[f4];
        int r = f4 >> 4, c4 = f4 & 15;
        xr[j] = *((const float4*)(xsrc + (size_t)r * 256 + c4 * 4));
      }
    }
    float acc[4][4];
#pragma unroll
    for (int r = 0; r < 4; ++r) {
      acc[r][0] = 0.f; acc[r][1] = 0.f; acc[r][2] = 0.f; acc[r][3] = 0.f;
    }
    for (int step = 0; step < 8; ++step) {
      const int ht2 = step >> 2;      // h-subtile (64 rows) within half
      __syncthreads();                // previous consumers done
      // store staged regs -> LDS
#pragma unroll
      for (int j = 0; j < 4; ++j) {
        int f4 = t + 256 * j;
        int r = f4 >> 4, c4 = f4 & 15;
        *((float4*)&tws[r][c4 * 4]) = twr[j];
        int g = (r >> 2) ^ c4;        // col-group XOR swizzle
        int col = (r & 3) + g * 4;
        xsT[c4 * 4 + 0][col] = xr[j].x;
        xsT[c4 * 4 + 1][col] = xr[j].y;
        xsT[c4 * 4 + 2][col] = xr[j].z;
        xsT[c4 * 4 + 3][col] = xr[j].w;
      }
      // prefetch next step (overlaps the compute below)
      if (step < 7) {
        const int ns = step + 1;
        const int nht2 = ns >> 2, nkc = ns & 3;
        const float4* tsrc = (const float4*)(twxA + nkc * 4096);
        const float* xsrc = xp + (size_t)(half * 128 + nht2 * 64) * 256 + nkc * 64;
#pragma unroll
        for (int j = 0; j < 4; ++j) {
          int f4 = t + 256 * j;
          twr[j] = tsrc[f4];
          int r = f4 >> 4, c4 = f4 & 15;
          xr[j] = *((const float4*)(xsrc + (size_t)r * 256 + c4 * 4));
        }
      }
      __syncthreads();
#pragma unroll 4
      for (int k = 0; k < 64; ++k) {
        float4 tw = *((const float4*)&tws[k][cg * 4]);
        float4 xv = *((const float4*)&xsT[k][4 * (rg ^ ((k >> 2) & 15))]);
        acc[0][0] = fmaf(xv.x, tw.x, acc[0][0]);
        acc[0][1] = fmaf(xv.x, tw.y, acc[0][1]);
        acc[0][2] = fmaf(xv.x, tw.z, acc[0][2]);
        acc[0][3] = fmaf(xv.x, tw.w, acc[0][3]);
        acc[1][0] = fmaf(xv.y, tw.x, acc[1][0]);
        acc[1][1] = fmaf(xv.y, tw.y, acc[1][1]);
        acc[1][2] = fmaf(xv.y, tw.z, acc[1][2]);
        acc[1][3] = fmaf(xv.y, tw.w, acc[1][3]);
        acc[2][0] = fmaf(xv.z, tw.x, acc[2][0]);
        acc[2][1] = fmaf(xv.z, tw.y, acc[2][1]);
        acc[2][2] = fmaf(xv.z, tw.z, acc[2][2]);
        acc[2][3] = fmaf(xv.z, tw.w, acc[2][3]);
        acc[3][0] = fmaf(xv.w, tw.x, acc[3][0]);
        acc[3][1] = fmaf(xv.w, tw.y, acc[3][1]);
        acc[3][2] = fmaf(xv.w, tw.z, acc[3][2]);
        acc[3][3] = fmaf(xv.w, tw.w, acc[3][3]);
      }
      if ((step & 3) == 3) {          // kc==3: h-subtile complete
        const int r0 = ht2 * 64 + rg * 4;
#pragma unroll
        for (int r = 0; r < 4; ++r) {
          *((float4*)&As[r0 + r][cg * 4]) =
              make_float4(acc[r][0], acc[r][1], acc[r][2], acc[r][3]);
          acc[r][0] = 0.f; acc[r][1] = 0.f; acc[r][2] = 0.f; acc[r][3] = 0.f;
        }
      }
    }
    __syncthreads();                  // As[128][64] complete for this half
    // B phase: accumulate conj-twiddle contraction over this half's h rows
    const float* ty = twyB + (size_t)(half * 128) * 128;
#pragma unroll 2
    for (int h = 0; h < 128; ++h) {
      float cy = ty[h * 128 + m];
      float sy = ty[h * 128 + 64 + m];
      float4 r0 = *((const float4*)&As[h][kx0]);
      float4 r1 = *((const float4*)&As[h][kx0 + 4]);
      float4 i0 = *((const float4*)&As[h][32 + kx0]);
      float4 i1 = *((const float4*)&As[h][32 + kx0 + 4]);
      // (Ar + iAi) * (cy - i sy):  re = Ar*cy + Ai*sy ; im = Ai*cy - Ar*sy
#define CMAC_B(j, rr, ii)                                   \
      accBr[j] = fmaf(rr, cy, fmaf(ii, sy, accBr[j]));      \
      accBi[j] = fmaf(ii, cy, fmaf(-(rr), sy, accBi[j]));
      CMAC_B(0, r0.x, i0.x) CMAC_B(1, r0.y, i0.y)
      CMAC_B(2, r0.z, i0.z) CMAC_B(3, r0.w, i0.w)
      CMAC_B(4, r1.x, i1.x) CMAC_B(5, r1.y, i1.y)
      CMAC_B(6, r1.z, i1.z) CMAC_B(7, r1.w, i1.w)
#undef CMAC_B
    }
  }
  float2* dst = X2 + (size_t)bi * 2048 + m * 32 + kx0;
  float4* d4 = (float4*)dst;
  d4[0] = make_float4(accBr[0], accBi[0], accBr[1], accBi[1]);
  d4[1] = make_float4(accBr[2], accBi[2], accBr[3], accBi[3]);
  d4[2] = make_float4(accBr[4], accBi[4], accBr[5], accBi[5]);
  d4[3] = make_float4(accBr[6], accBi[6], accBr[7], accBi[7]);
}

// ---------------- C: channel mix (one block per mode, XCD-chunked) ----------------
__global__ __launch_bounds__(256, 4) void k_C(const float2* __restrict__ X2,
                                              const float* __restrict__ wpr,
                                              const float* __restrict__ wpi,
                                              const float* __restrict__ wnr,
                                              const float* __restrict__ wni,
                                              float2* __restrict__ Cc) {
  __shared__ float2 Xs[16][64];    // [b][i]
  __shared__ float2 Wsh[64][64];   // [i][o]
  const int t = threadIdx.x;
  const int bid = blockIdx.x;
  const int mode = (bid & 7) * 256 + (bid >> 3);   // bijective XCD-chunked map
  const float* wr; const float* wi; int wm;
  if (mode < 1024) { wr = wpr; wi = wpi; wm = mode; }
  else             { wr = wnr; wi = wni; wm = mode - 1024; }

  float2 xv[4];
#pragma unroll
  for (int j = 0; j < 4; ++j) {
    int bi = t + 256 * j;                        // b = bi>>6, i = bi&63
    xv[j] = X2[(size_t)bi * 2048 + mode];
  }
  float wre[16], wim[16];
#pragma unroll
  for (int k = 0; k < 16; ++k) {
    int io = t + 256 * k;                        // i = io>>6, o = io&63
    size_t a = (size_t)io * 1024 + wm;
    wre[k] = wr[a];
    wim[k] = wi[a];
  }
#pragma unroll
  for (int j = 0; j < 4; ++j) {
    int bi = t + 256 * j;
    Xs[bi >> 6][bi & 63] = xv[j];
  }
#pragma unroll
  for (int k = 0; k < 16; ++k) {
    int io = t + 256 * k;
    Wsh[io >> 6][io & 63] = make_float2(wre[k], wim[k]);
  }
  __syncthreads();

  const int o = t & 63, bg = t >> 6;             // bg wave-uniform
  float accr[4] = {0.f, 0.f, 0.f, 0.f};
  float acci[4] = {0.f, 0.f, 0.f, 0.f};
#pragma unroll 4
  for (int i = 0; i < 64; ++i) {
    float2 w = Wsh[i][o];
    float2 x0 = Xs[bg * 4 + 0][i];
    float2 x1 = Xs[bg * 4 + 1][i];
    float2 x2 = Xs[bg * 4 + 2][i];
    float2 x3 = Xs[bg * 4 + 3][i];
    accr[0] = fmaf(x0.x, w.x, fmaf(-x0.y, w.y, accr[0]));
    acci[0] = fmaf(x0.x, w.y, fmaf( x0.y, w.x, acci[0]));
    accr[1] = fmaf(x1.x, w.x, fmaf(-x1.y, w.y, accr[1]));
    acci[1] = fmaf(x1.x, w.y, fmaf( x1.y, w.x, acci[1]));
    accr[2] = fmaf(x2.x, w.x, fmaf(-x2.y, w.y, accr[2]));
    acci[2] = fmaf(x2.x, w.y, fmaf( x2.y, w.x, acci[2]));
    accr[3] = fmaf(x3.x, w.x, fmaf(-x3.y, w.y, accr[3]));
    acci[3] = fmaf(x3.x, w.y, fmaf( x3.y, w.x, acci[3]));
  }

  const float scale = (((mode & 31) == 0) ? 1.f : 2.f) * (1.f / 65536.f);
#pragma unroll
  for (int j = 0; j < 4; ++j) {
    int b = bg * 4 + j;
    Cc[(size_t)(b * 64 + o) * 2048 + mode] =
        make_float2(accr[j] * scale, acci[j] * scale);
  }
}

// ---------------- DE: inverse y-DFT + inverse x-DFT + Re() fused ----------------
// grid 1024 (b*64+o); block 256. Two 128-h halves:
//   D phase: Ys[128][68] = inverse-y (cols 0..31 Re, 32..63 -Im); pad 68 keeps
//            the float4 writes at bank-minimum.
//   E phase: out rows = Ys-row (wave-uniform broadcast) dot twxT columns.
__global__ __launch_bounds__(256, 2) void k_DE(const float2* __restrict__ Cc,
                                               const float* __restrict__ twyT,
                                               const float* __restrict__ twxT,
                                               float* __restrict__ out) {
  __shared__ float Cr[64][36], Ci[64][36];
  __shared__ float Ys[128][68];
  const int t = threadIdx.x, bo = blockIdx.x;
  const float4* Cp = (const float4*)(Cc + (size_t)bo * 2048);
#pragma unroll
  for (int j = 0; j < 4; ++j) {
    int f4 = t + 256 * j;
    float4 v = Cp[f4];
    int mode = f4 * 2;
    int mm = mode >> 5, kx = mode & 31;
    Cr[mm][kx]     = v.x; Ci[mm][kx]     = v.y;
    Cr[mm][kx + 1] = v.z; Ci[mm][kx + 1] = v.w;
  }
  const int kx0 = (t & 3) * 8, hs = t >> 2;
  const int wg = t & 63, rg = t >> 6;
  const float* cyp = twyT;
  const float* syp = twyT + 16384;
  const float4* twp = (const float4*)twxT;
  float* outp = out + (size_t)bo * 65536;
  __syncthreads();

  for (int half = 0; half < 2; ++half) {
    // D phase
    for (int hp = 0; hp < 2; ++hp) {
      const int hloc = hp * 64 + hs;          // 0..127
      const int h = half * 128 + hloc;
      float accr[8] = {0,0,0,0,0,0,0,0};
      float accn[8] = {0,0,0,0,0,0,0,0};
#pragma unroll 2
      for (int mm = 0; mm < 64; ++mm) {
        float cy = cyp[mm * 256 + h];
        float sy = syp[mm * 256 + h];
        float4 c0 = *((const float4*)&Cr[mm][kx0]);
        float4 c1 = *((const float4*)&Cr[mm][kx0 + 4]);
        float4 d0 = *((const float4*)&Ci[mm][kx0]);
        float4 d1 = *((const float4*)&Ci[mm][kx0 + 4]);
        // Y = sum C * (cy + i sy): re = Cr*cy - Ci*sy ; neg-im = -(Cr*sy + Ci*cy)
#define DMAC(j, rr, ii)                                       \
        accr[j] = fmaf(rr, cy, fmaf(-(ii), sy, accr[j]));     \
        accn[j] = fmaf(-(rr), sy, fmaf(-(ii), cy, accn[j]));
        DMAC(0, c0.x, d0.x) DMAC(1, c0.y, d0.y)
        DMAC(2, c0.z, d0.z) DMAC(3, c0.w, d0.w)
        DMAC(4, c1.x, d1.x) DMAC(5, c1.y, d1.y)
        DMAC(6, c1.z, d1.z) DMAC(7, c1.w, d1.w)
#undef DMAC
      }
      *((float4*)&Ys[hloc][kx0])      = make_float4(accr[0], accr[1], accr[2], accr[3]);
      *((float4*)&Ys[hloc][kx0 + 4])  = make_float4(accr[4], accr[5], accr[6], accr[7]);
      *((float4*)&Ys[hloc][32 + kx0]) = make_float4(accn[0], accn[1], accn[2], accn[3]);
      *((float4*)&Ys[hloc][36 + kx0]) = make_float4(accn[4], accn[5], accn[6], accn[7]);
    }
    __syncthreads();
    // E phase: 4 row-chunks of 32
    for (int rc = 0; rc < 4; ++rc) {
      float acc[8][4];
#pragma unroll
      for (int r = 0; r < 8; ++r) {
        acc[r][0] = 0.f; acc[r][1] = 0.f; acc[r][2] = 0.f; acc[r][3] = 0.f;
      }
#pragma unroll 2
      for (int k = 0; k < 64; ++k) {
        float4 tw = twp[k * 64 + wg];
#pragma unroll
        for (int r = 0; r < 8; ++r) {
          float yv = Ys[rc * 32 + rg * 8 + r][k];   // wave-uniform row -> broadcast
          acc[r][0] = fmaf(yv, tw.x, acc[r][0]);
          acc[r][1] = fmaf(yv, tw.y, acc[r][1]);
          acc[r][2] = fmaf(yv, tw.z, acc[r][2]);
          acc[r][3] = fmaf(yv, tw.w, acc[r][3]);
        }
      }
#pragma unroll
      for (int r = 0; r < 8; ++r) {
        size_t row = (size_t)half * 128 + rc * 32 + rg * 8 + r;
        *((float4*)(outp + row * 256 + wg * 4)) =
            make_float4(acc[r][0], acc[r][1], acc[r][2], acc[r][3]);
      }
    }
    __syncthreads();   // before next half's D overwrites Ys
  }
}

extern "C" void kernel_launch(void* const* d_in, const int* in_sizes, int n_in,
                              void* d_out, int out_size, void* d_ws, size_t ws_size,
                              hipStream_t stream) {
  (void)in_sizes; (void)n_in; (void)out_size; (void)ws_size;
  const float* x   = (const float*)d_in[0];
  const float* wpr = (const float*)d_in[1];
  const float* wpi = (const float*)d_in[2];
  const float* wnr = (const float*)d_in[3];
  const float* wni = (const float*)d_in[4];
  float* out = (float*)d_out;
  float* ws  = (float*)d_ws;

  float2* X2 = (float2*)(ws + T_X2);   // [1024][2048] float2 = 16.8 MB
  float2* Cc = (float2*)(ws + T_CC);   // [1024][2048] float2 = 16.8 MB

  k_prep<<<384, 256, 0, stream>>>(ws);
  k_AB<<<1024, 256, 0, stream>>>(x, ws + T_TWXA, ws + T_TWYB, X2);
  k_C<<<2048, 256, 0, stream>>>(X2, wpr, wpi, wnr, wni, Cc);
  k_DE<<<1024, 256, 0, stream>>>(Cc, ws + T_TWYT, ws + T_TWXT, out);
}

// Round 6
// 469.870 us; speedup vs baseline: 1.3081x; 1.3081x over previous
//
#include <hip/hip_runtime.h>
#include <math.h>

#define PI_F 3.14159265358979323846f

// Problem constants (fixed by reference):
// x:[16][64][256][256] f32, weights ×4:[64][64][32][32] f32, out:[16][64][256][256] f32
// modes: ky m=0..63 -> ky = m (m<32) else m+192 ; kx = 0..31
//
// Pipeline (A1/X2/Cc scratch in d_out, Y1 + tables in d_ws):
//   A: A1[bi][h][64] = x-DFT via bf16-split MFMA (cols 0..31 Re, 32..63 Im(-sin))
//   B: X2[bi][mode]  = y-DFT over h (conj twiddle), fp32 vector
//   C: Cc[b*64+o][mode] = channel mix, fp32 vector, XCD-chunked
//   D: Y1[bo][h][64] = inverse-y (cols 0..31 Re, 32..63 -Im), fp32 vector
//   E: out = inverse-x + Re() via bf16-split MFMA

static constexpr int T_TWXA = 0;        // [256 w][64] fp32 (unused by MFMA A; kept)
static constexpr int T_TWYB = 16384;    // [256 h][128]  cos[64] | sin[64] at ky(m)
static constexpr int T_TWYT = 49152;    // [2][64 m][256 h]  cos plane, sin plane
static constexpr int T_TWXT = 81920;    // [64][256] fp32 (unused by MFMA E; kept)
static constexpr int T_FA   = 98304;    // bf16 frag table TwX: hi[16384], lo[16384]
static constexpr int T_FE   = 114688;   // bf16 frag table TwXT: hi[16384], lo[16384]
static constexpr int T_Y1   = 131072;   // [1024 bo][256 h][64] fp32

typedef __attribute__((ext_vector_type(8))) __bf16 bf16x8;
typedef __attribute__((ext_vector_type(4))) float f32x4;

// ---------------- twiddle tables + bf16 fragment tables ----------------
__global__ __launch_bounds__(256) void k_prep(float* __restrict__ ws) {
  int idx = blockIdx.x * 256 + threadIdx.x;
  if (idx < 16384) {
    int w = idx >> 6, col = idx & 63, k = col & 31;
    float ang = (2.0f * PI_F / 256.0f) * (float)((k * w) & 255);
    ws[T_TWXA + idx] = (col < 32) ? cosf(ang) : -sinf(ang);
  } else if (idx < 49152) {
    int j = idx - 16384;
    int h = j >> 7, col = j & 127, m = col & 63;
    int ky = (m < 32) ? m : (m + 192);
    float ang = (2.0f * PI_F / 256.0f) * (float)((ky * h) & 255);
    ws[idx] = (col < 64) ? cosf(ang) : sinf(ang);
  } else if (idx < 81920) {
    int j = idx - 49152;
    int part = j >> 14, m = (j >> 8) & 63, h = j & 255;
    int ky = (m < 32) ? m : (m + 192);
    float ang = (2.0f * PI_F / 256.0f) * (float)((ky * h) & 255);
    ws[idx] = part ? sinf(ang) : cosf(ang);
  } else if (idx < 98304) {
    int j = idx - 81920;
    int row = j >> 8, w = j & 255, k = row & 31;
    float ang = (2.0f * PI_F / 256.0f) * (float)((k * w) & 255);
    ws[idx] = (row < 32) ? cosf(ang) : sinf(ang);
  } else if (idx < 114688) {
    // TwX B-fragments for mfma 16x16x32: fid = kc*4+nsub (kc<8, nsub<4)
    // entry j = (fid*64 + lane)*8 + e ; value = TwX[w][col]
    int j = idx - 98304;
    int e = j & 7, l = (j >> 3) & 63, q = j >> 9;    // q = fid 0..31
    int ns = q & 3, kc = q >> 2;
    int w = kc * 32 + (l >> 4) * 8 + e;              // K dim = w 0..255
    int col = ns * 16 + (l & 15);                    // N dim = col 0..63
    int kxi = col & 31;
    float ang = (2.0f * PI_F / 256.0f) * (float)((kxi * w) & 255);
    float v = (col < 32) ? cosf(ang) : -sinf(ang);
    __bf16 hv = (__bf16)v;
    __bf16 lv = (__bf16)(v - (float)hv);
    __bf16* fr = (__bf16*)(ws + T_FA);
    fr[j] = hv; fr[16384 + j] = lv;
  } else if (idx < 131072) {
    // TwXT B-fragments: fid = kc*16 + wblk (kc<2, wblk<16)
    // entry j = (fid*64 + lane)*8 + e ; value = TwXT[c][w]
    int j = idx - 114688;
    int e = j & 7, l = (j >> 3) & 63, q = j >> 9;    // q = fid 0..31
    int wb = q & 15, kc = q >> 4;
    int c = kc * 32 + (l >> 4) * 8 + e;              // K dim = c 0..63
    int w = wb * 16 + (l & 15);                      // N dim = w 0..255
    int kxi = (c < 32) ? c : (c - 32);
    float ang = (2.0f * PI_F / 256.0f) * (float)((kxi * w) & 255);
    float v = (c < 32) ? cosf(ang) : sinf(ang);
    __bf16 hv = (__bf16)v;
    __bf16 lv = (__bf16)(v - (float)hv);
    __bf16* fr = (__bf16*)(ws + T_FE);
    fr[j] = hv; fr[16384 + j] = lv;
  }
}

// split 8 consecutive floats into hi/lo bf16x8 fragments
__device__ __forceinline__ void cvt_split8(const float* __restrict__ p,
                                           bf16x8& h, bf16x8& l) {
  float4 a = *(const float4*)p;
  float4 b = *(const float4*)(p + 4);
#define CVS(e, vv) { __bf16 hh = (__bf16)(vv); h[e] = hh; l[e] = (__bf16)((vv) - (float)hh); }
  CVS(0, a.x) CVS(1, a.y) CVS(2, a.z) CVS(3, a.w)
  CVS(4, b.x) CVS(5, b.y) CVS(6, b.z) CVS(7, b.w)
#undef CVS
}

// ---------------- A: forward x-DFT via bf16-split MFMA ----------------
// Per block (grid 1024 = b*64+i): A1[256 h][64] = x[256 h][256 w] · TwX[256][64].
// Wave wv owns rows wv*64..+63 (4 M-subtiles × 4 N-subtiles of 16×16, K-loop 8×32).
// A-frags read direct from global: lanes' 4 k-groups tile 128B/row -> full lines.
__global__ __launch_bounds__(256) void k_A(const float* __restrict__ x,
                                           const float* __restrict__ ws,
                                           float* __restrict__ A1) {
  const __bf16* frA = (const __bf16*)(ws + T_FA);
  const int t = threadIdx.x, bi = blockIdx.x;
  const int l = t & 63, wv = t >> 6;
  const int lr = l & 15, lk = l >> 4;
  f32x4 acc[4][4];
#pragma unroll
  for (int m = 0; m < 4; ++m)
#pragma unroll
    for (int n = 0; n < 4; ++n) acc[m][n] = (f32x4){0.f, 0.f, 0.f, 0.f};

  const float* xb = x + (size_t)bi * 65536 + (size_t)(wv * 64 + lr) * 256 + lk * 8;
  for (int kc = 0; kc < 8; ++kc) {
    bf16x8 ah[4], al[4];
#pragma unroll
    for (int ms = 0; ms < 4; ++ms)
      cvt_split8(xb + ms * 16 * 256 + kc * 32, ah[ms], al[ms]);
    bf16x8 bh[4], bl[4];
#pragma unroll
    for (int ns = 0; ns < 4; ++ns) {
      int fo = ((kc * 4 + ns) * 64 + l) * 8;
      bh[ns] = *(const bf16x8*)(frA + fo);
      bl[ns] = *(const bf16x8*)(frA + 16384 + fo);
    }
#pragma unroll
    for (int ms = 0; ms < 4; ++ms)
#pragma unroll
      for (int ns = 0; ns < 4; ++ns) {
        acc[ms][ns] = __builtin_amdgcn_mfma_f32_16x16x32_bf16(ah[ms], bh[ns], acc[ms][ns], 0, 0, 0);
        acc[ms][ns] = __builtin_amdgcn_mfma_f32_16x16x32_bf16(al[ms], bh[ns], acc[ms][ns], 0, 0, 0);
        acc[ms][ns] = __builtin_amdgcn_mfma_f32_16x16x32_bf16(ah[ms], bl[ns], acc[ms][ns], 0, 0, 0);
      }
  }
  // C/D layout: col = lane&15, row = (lane>>4)*4 + reg  [m89-verified]
  float* Ab = A1 + (size_t)bi * 16384;
#pragma unroll
  for (int ms = 0; ms < 4; ++ms)
#pragma unroll
    for (int ns = 0; ns < 4; ++ns) {
      int col = ns * 16 + lr;
      int row0 = wv * 64 + ms * 16 + lk * 4;
#pragma unroll
      for (int r = 0; r < 4; ++r)
        Ab[(size_t)(row0 + r) * 64 + col] = acc[ms][ns][r];
    }
}

// ---------------- B: forward y-DFT (fp32, as R4) ----------------
__global__ __launch_bounds__(256) void k_B(const float* __restrict__ A1,
                                           const float* __restrict__ twyB,
                                           float2* __restrict__ X2) {
  __shared__ float as[64][68];
  const int t = threadIdx.x, bi = blockIdx.x;
  const int m = t >> 2, kx0 = (t & 3) * 8;
  float accr[8] = {0,0,0,0,0,0,0,0};
  float acci[8] = {0,0,0,0,0,0,0,0};
  const float* Ap = A1 + (size_t)bi * 16384;
  for (int hc = 0; hc < 4; ++hc) {
    __syncthreads();
    const float4* src = (const float4*)(Ap + hc * 4096);
#pragma unroll
    for (int j = 0; j < 4; ++j) {
      int f4 = t + 256 * j;
      int r = f4 >> 4, c4 = f4 & 15;
      *((float4*)&as[r][c4 * 4]) = src[f4];
    }
    __syncthreads();
    const float* ty = twyB + hc * 64 * 128;
#pragma unroll 2
    for (int h = 0; h < 64; ++h) {
      float cy = ty[h * 128 + m];
      float sy = ty[h * 128 + 64 + m];
      float4 r0 = *((const float4*)&as[h][kx0]);
      float4 r1 = *((const float4*)&as[h][kx0 + 4]);
      float4 i0 = *((const float4*)&as[h][32 + kx0]);
      float4 i1 = *((const float4*)&as[h][32 + kx0 + 4]);
#define CMAC_B(j, rr, ii)                                   \
      accr[j] = fmaf(rr, cy, fmaf(ii, sy, accr[j]));        \
      acci[j] = fmaf(ii, cy, fmaf(-(rr), sy, acci[j]));
      CMAC_B(0, r0.x, i0.x) CMAC_B(1, r0.y, i0.y)
      CMAC_B(2, r0.z, i0.z) CMAC_B(3, r0.w, i0.w)
      CMAC_B(4, r1.x, i1.x) CMAC_B(5, r1.y, i1.y)
      CMAC_B(6, r1.z, i1.z) CMAC_B(7, r1.w, i1.w)
#undef CMAC_B
    }
  }
  float2* dst = X2 + (size_t)bi * 2048 + m * 32 + kx0;
  float4* d4 = (float4*)dst;
  d4[0] = make_float4(accr[0], acci[0], accr[1], acci[1]);
  d4[1] = make_float4(accr[2], acci[2], accr[3], acci[3]);
  d4[2] = make_float4(accr[4], acci[4], accr[5], acci[5]);
  d4[3] = make_float4(accr[6], acci[6], accr[7], acci[7]);
}

// ---------------- C: channel mix (one block per mode, XCD-chunked) ----------------
__global__ __launch_bounds__(256, 4) void k_C(const float2* __restrict__ X2,
                                              const float* __restrict__ wpr,
                                              const float* __restrict__ wpi,
                                              const float* __restrict__ wnr,
                                              const float* __restrict__ wni,
                                              float2* __restrict__ Cc) {
  __shared__ float2 Xs[16][64];    // [b][i]
  __shared__ float2 Wsh[64][64];   // [i][o]
  const int t = threadIdx.x;
  const int bid = blockIdx.x;
  const int mode = (bid & 7) * 256 + (bid >> 3);   // bijective XCD-chunked map
  const float* wr; const float* wi; int wm;
  if (mode < 1024) { wr = wpr; wi = wpi; wm = mode; }
  else             { wr = wnr; wi = wni; wm = mode - 1024; }

  float2 xv[4];
#pragma unroll
  for (int j = 0; j < 4; ++j) {
    int bi = t + 256 * j;
    xv[j] = X2[(size_t)bi * 2048 + mode];
  }
  float wre[16], wim[16];
#pragma unroll
  for (int k = 0; k < 16; ++k) {
    int io = t + 256 * k;
    size_t a = (size_t)io * 1024 + wm;
    wre[k] = wr[a];
    wim[k] = wi[a];
  }
#pragma unroll
  for (int j = 0; j < 4; ++j) {
    int bi = t + 256 * j;
    Xs[bi >> 6][bi & 63] = xv[j];
  }
#pragma unroll
  for (int k = 0; k < 16; ++k) {
    int io = t + 256 * k;
    Wsh[io >> 6][io & 63] = make_float2(wre[k], wim[k]);
  }
  __syncthreads();

  const int o = t & 63, bg = t >> 6;
  float accr[4] = {0.f, 0.f, 0.f, 0.f};
  float acci[4] = {0.f, 0.f, 0.f, 0.f};
#pragma unroll 4
  for (int i = 0; i < 64; ++i) {
    float2 w = Wsh[i][o];
    float2 x0 = Xs[bg * 4 + 0][i];
    float2 x1 = Xs[bg * 4 + 1][i];
    float2 x2 = Xs[bg * 4 + 2][i];
    float2 x3 = Xs[bg * 4 + 3][i];
    accr[0] = fmaf(x0.x, w.x, fmaf(-x0.y, w.y, accr[0]));
    acci[0] = fmaf(x0.x, w.y, fmaf( x0.y, w.x, acci[0]));
    accr[1] = fmaf(x1.x, w.x, fmaf(-x1.y, w.y, accr[1]));
    acci[1] = fmaf(x1.x, w.y, fmaf( x1.y, w.x, acci[1]));
    accr[2] = fmaf(x2.x, w.x, fmaf(-x2.y, w.y, accr[2]));
    acci[2] = fmaf(x2.x, w.y, fmaf( x2.y, w.x, acci[2]));
    accr[3] = fmaf(x3.x, w.x, fmaf(-x3.y, w.y, accr[3]));
    acci[3] = fmaf(x3.x, w.y, fmaf( x3.y, w.x, acci[3]));
  }

  const float scale = (((mode & 31) == 0) ? 1.f : 2.f) * (1.f / 65536.f);
#pragma unroll
  for (int j = 0; j < 4; ++j) {
    int b = bg * 4 + j;
    Cc[(size_t)(b * 64 + o) * 2048 + mode] =
        make_float2(accr[j] * scale, acci[j] * scale);
  }
}

// ---------------- D: inverse y-DFT (fp32, as R4) ----------------
__global__ __launch_bounds__(256) void k_D(const float2* __restrict__ Cc,
                                           const float* __restrict__ twyT,
                                           float* __restrict__ Y1) {
  __shared__ float Cr[64][36], Ci[64][36];
  const int t = threadIdx.x, bo = blockIdx.x;
  const float4* Cp = (const float4*)(Cc + (size_t)bo * 2048);
#pragma unroll
  for (int j = 0; j < 4; ++j) {
    int f4 = t + 256 * j;
    float4 v = Cp[f4];
    int mode = f4 * 2;
    int mm = mode >> 5, kx = mode & 31;
    Cr[mm][kx]     = v.x; Ci[mm][kx]     = v.y;
    Cr[mm][kx + 1] = v.z; Ci[mm][kx + 1] = v.w;
  }
  __syncthreads();
  const int kx0 = (t & 3) * 8, hs = t >> 2;
  const float* cyp = twyT;
  const float* syp = twyT + 16384;
  for (int hp = 0; hp < 4; ++hp) {
    const int h = hp * 64 + hs;
    float accr[8] = {0,0,0,0,0,0,0,0};
    float accn[8] = {0,0,0,0,0,0,0,0};
#pragma unroll 2
    for (int mm = 0; mm < 64; ++mm) {
      float cy = cyp[mm * 256 + h];
      float sy = syp[mm * 256 + h];
      float4 c0 = *((const float4*)&Cr[mm][kx0]);
      float4 c1 = *((const float4*)&Cr[mm][kx0 + 4]);
      float4 d0 = *((const float4*)&Ci[mm][kx0]);
      float4 d1 = *((const float4*)&Ci[mm][kx0 + 4]);
#define DMAC(j, rr, ii)                                       \
      accr[j] = fmaf(rr, cy, fmaf(-(ii), sy, accr[j]));       \
      accn[j] = fmaf(-(rr), sy, fmaf(-(ii), cy, accn[j]));
      DMAC(0, c0.x, d0.x) DMAC(1, c0.y, d0.y)
      DMAC(2, c0.z, d0.z) DMAC(3, c0.w, d0.w)
      DMAC(4, c1.x, d1.x) DMAC(5, c1.y, d1.y)
      DMAC(6, c1.z, d1.z) DMAC(7, c1.w, d1.w)
#undef DMAC
    }
    float* dst = Y1 + (size_t)bo * 16384 + (size_t)h * 64 + kx0;
    *((float4*)(dst + 0))  = make_float4(accr[0], accr[1], accr[2], accr[3]);
    *((float4*)(dst + 4))  = make_float4(accr[4], accr[5], accr[6], accr[7]);
    *((float4*)(dst + 32)) = make_float4(accn[0], accn[1], accn[2], accn[3]);
    *((float4*)(dst + 36)) = make_float4(accn[4], accn[5], accn[6], accn[7]);
  }
}

// ---------------- E: inverse x-DFT + Re() via bf16-split MFMA ----------------
// Per block (grid 1024 = b*64+o): out[256 h][256 w] = Y1[256 h][64] · TwXT[64][256].
// Wave wv owns rows wv*64..+63; col-blocks of 64 looped (acc reset each).
__global__ __launch_bounds__(256) void k_E(const float* __restrict__ Y1,
                                           const float* __restrict__ ws,
                                           float* __restrict__ out) {
  const __bf16* frE = (const __bf16*)(ws + T_FE);
  const int t = threadIdx.x, bo = blockIdx.x;
  const int l = t & 63, wv = t >> 6;
  const int lr = l & 15, lk = l >> 4;

  // A-frags: Y1 rows, K=64 (kc 0..1), loaded once
  bf16x8 ah[4][2], al[4][2];
  const float* yb = Y1 + (size_t)bo * 16384 + (size_t)(wv * 64 + lr) * 64 + lk * 8;
#pragma unroll
  for (int ms = 0; ms < 4; ++ms)
#pragma unroll
    for (int kc = 0; kc < 2; ++kc)
      cvt_split8(yb + ms * 16 * 64 + kc * 32, ah[ms][kc], al[ms][kc]);

  float* ob = out + (size_t)bo * 65536;
  for (int cb = 0; cb < 4; ++cb) {
    f32x4 acc[4][4];
#pragma unroll
    for (int m = 0; m < 4; ++m)
#pragma unroll
      for (int n = 0; n < 4; ++n) acc[m][n] = (f32x4){0.f, 0.f, 0.f, 0.f};
#pragma unroll
    for (int kc = 0; kc < 2; ++kc) {
      bf16x8 bh[4], bl[4];
#pragma unroll
      for (int ns = 0; ns < 4; ++ns) {
        int fo = ((kc * 16 + cb * 4 + ns) * 64 + l) * 8;
        bh[ns] = *(const bf16x8*)(frE + fo);
        bl[ns] = *(const bf16x8*)(frE + 16384 + fo);
      }
#pragma unroll
      for (int ms = 0; ms < 4; ++ms)
#pragma unroll
        for (int ns = 0; ns < 4; ++ns) {
          acc[ms][ns] = __builtin_amdgcn_mfma_f32_16x16x32_bf16(ah[ms][kc], bh[ns], acc[ms][ns], 0, 0, 0);
          acc[ms][ns] = __builtin_amdgcn_mfma_f32_16x16x32_bf16(al[ms][kc], bh[ns], acc[ms][ns], 0, 0, 0);
          acc[ms][ns] = __builtin_amdgcn_mfma_f32_16x16x32_bf16(ah[ms][kc], bl[ns], acc[ms][ns], 0, 0, 0);
        }
    }
#pragma unroll
    for (int ms = 0; ms < 4; ++ms)
#pragma unroll
      for (int ns = 0; ns < 4; ++ns) {
        int col = cb * 64 + ns * 16 + lr;
        int row0 = wv * 64 + ms * 16 + lk * 4;
#pragma unroll
        for (int r = 0; r < 4; ++r)
          ob[(size_t)(row0 + r) * 256 + col] = acc[ms][ns][r];
      }
  }
}

extern "C" void kernel_launch(void* const* d_in, const int* in_sizes, int n_in,
                              void* d_out, int out_size, void* d_ws, size_t ws_size,
                              hipStream_t stream) {
  (void)in_sizes; (void)n_in; (void)out_size; (void)ws_size;
  const float* x   = (const float*)d_in[0];
  const float* wpr = (const float*)d_in[1];
  const float* wpi = (const float*)d_in[2];
  const float* wnr = (const float*)d_in[3];
  const float* wni = (const float*)d_in[4];
  float* out = (float*)d_out;
  float* ws  = (float*)d_ws;

  // scratch inside d_out (fully overwritten by k_E at the end):
  float*  A1 = out;                                   // [1024][256][64]
  float2* X2 = (float2*)(out + 16777216);             // [1024][2048] float2
  float2* Cc = (float2*)(out + 16777216 + 4194304);   // [1024][2048] float2
  float*  Y1 = ws + T_Y1;                             // [1024][256][64]

  k_prep<<<512, 256, 0, stream>>>(ws);
  k_A<<<1024, 256, 0, stream>>>(x, ws, A1);
  k_B<<<1024, 256, 0, stream>>>(A1, ws + T_TWYB, X2);
  k_C<<<2048, 256, 0, stream>>>(X2, wpr, wpi, wnr, wni, Cc);
  k_D<<<1024, 256, 0, stream>>>(Cc, ws + T_TWYT, Y1);
  k_E<<<1024, 256, 0, stream>>>(Y1, ws, out);
}

// Round 7
// 292.629 us; speedup vs baseline: 2.1004x; 1.6057x over previous
//
#include <hip/hip_runtime.h>
#include <math.h>

#define PI_F 3.14159265358979323846f

// x:[16][64][256][256] f32, weights ×4:[64][64][32][32] f32, out:[16][64][256][256] f32
// modes: ky m=0..63 -> ky = m (m<32) else m+192 ; kx = 0..31
//
// Fully-MFMA pipeline (X2/Cc + frag tables in d_ws; no A1/Y1 HBM round-trips):
//   AB: per bi: x-DFT MFMA (acc -> LDS in B-frag layout, bf16 hi/lo) ->
//       y-DFT MFMA (Cy/Sy twiddle-frag A-operand) -> X2[bi][mode] float2
//   C : Cc[b*64+o][mode] = channel mix, fp32 vector, XCD-chunked
//   DE: per bo: inverse-y MFMA (Tre/Tnim A-operand, K=128 stacked Cr/Ci; Cc
//       staged to LDS B-frags) -> Y scattered to LDS in E's A-frag layout
//       (wave-local) -> inverse-x MFMA -> out
//
// All fragment layouts mirror the R6-validated k_A/k_E conventions:
//   A-frag: row = lane&15, k = (lane>>4)*8 + e
//   B-frag: col = lane&15, k = (lane>>4)*8 + e
//   C/D   : col = lane&15, row = (lane>>4)*4 + reg

static constexpr int T_FA  = 0;         // x-DFT B-frag table  hi|lo  (32768 bf16)
static constexpr int T_FE  = 16384;     // inv-x  B-frag table hi|lo  (32768 bf16)
static constexpr int T_FBC = 32768;     // y-DFT Cy A-frag     hi|lo  (32768 bf16)
static constexpr int T_FBS = 49152;     // y-DFT Sy A-frag     hi|lo  (32768 bf16)
static constexpr int T_FDR = 65536;     // inv-y Tre A-frag    hi|lo  (65536 bf16)
static constexpr int T_FDN = 98304;     // inv-y Tnim A-frag   hi|lo  (65536 bf16)
static constexpr int T_X2  = 131072;                 // [1024][2048] float2
static constexpr int T_CC  = 131072 + 4194304;       // [1024][2048] float2

typedef __attribute__((ext_vector_type(8))) __bf16 bf16x8;
typedef __attribute__((ext_vector_type(4))) float f32x4;

// ---------------- fragment tables ----------------
__global__ __launch_bounds__(256) void k_prep(float* __restrict__ ws) {
  int idx = blockIdx.x * 256 + threadIdx.x;
  const float C = 2.0f * PI_F / 256.0f;
  if (idx < 16384) {
    // FA: B[n=col][k=w]; frag q = kc*4+ns (kc<8)
    int j = idx;
    int e = j & 7, l = (j >> 3) & 63, q = j >> 9;
    int ns = q & 3, kc = q >> 2;
    int w = kc * 32 + ((l >> 4) & 3) * 8 + e;
    int col = ns * 16 + (l & 15);
    int kxi = col & 31;
    float ang = C * (float)((kxi * w) & 255);
    float v = (col < 32) ? cosf(ang) : -sinf(ang);
    __bf16 hv = (__bf16)v;
    __bf16 lv = (__bf16)(v - (float)hv);
    __bf16* fr = (__bf16*)(ws + T_FA);
    fr[j] = hv; fr[16384 + j] = lv;
  } else if (idx < 32768) {
    // FE: B[n=w][k=c]; frag q = kc*16+wblk (kc<2)
    int j = idx - 16384;
    int e = j & 7, l = (j >> 3) & 63, q = j >> 9;
    int wb = q & 15, kc = q >> 4;
    int c = kc * 32 + ((l >> 4) & 3) * 8 + e;
    int w = wb * 16 + (l & 15);
    int kxi = (c < 32) ? c : (c - 32);
    float ang = C * (float)((kxi * w) & 255);
    float v = (c < 32) ? cosf(ang) : sinf(ang);
    __bf16 hv = (__bf16)v;
    __bf16 lv = (__bf16)(v - (float)hv);
    __bf16* fr = (__bf16*)(ws + T_FE);
    fr[j] = hv; fr[16384 + j] = lv;
  } else if (idx < 65536) {
    // FBC/FBS: A[row=m][k=h]; frag q = kc*4+ms4 (kc<8)
    int base = (idx < 49152) ? 32768 : 49152;
    int j = idx - base;
    int e = j & 7, l = (j >> 3) & 63, q = j >> 9;
    int ms4 = q & 3, kc = q >> 2;
    int m = ms4 * 16 + (l & 15);
    int h = kc * 32 + ((l >> 4) & 3) * 8 + e;
    int ky = (m < 32) ? m : (m + 192);
    float ang = C * (float)((ky * h) & 255);
    float v = (idx < 49152) ? cosf(ang) : sinf(ang);
    __bf16 hv = (__bf16)v;
    __bf16 lv = (__bf16)(v - (float)hv);
    __bf16* fr = (__bf16*)(ws + base);
    fr[j] = hv; fr[16384 + j] = lv;
  } else if (idx < 131072) {
    // FDR/FDN: A[row=h][k=stacked m]; frag f = msG*4+kc (msG<16, kc<4)
    int base = (idx < 98304) ? 65536 : 98304;
    int j = idx - base;
    int e = j & 7, l = (j >> 3) & 63, f = j >> 9;
    int msG = f >> 2, kc = f & 3;
    int h = msG * 16 + (l & 15);
    int k = kc * 32 + ((l >> 4) & 3) * 8 + e;
    int m = (k < 64) ? k : (k - 64);
    int ky = (m < 32) ? m : (m + 192);
    float ang = C * (float)((ky * h) & 255);
    float cv = cosf(ang), sv = sinf(ang);
    float v;
    if (idx < 98304) v = (k < 64) ? cv : -sv;    // Tre:  cy | -sy
    else             v = (k < 64) ? -sv : -cv;   // Tnim: -sy | -cy
    __bf16 hv = (__bf16)v;
    __bf16 lv = (__bf16)(v - (float)hv);
    __bf16* fr = (__bf16*)(ws + base);
    fr[j] = hv; fr[32768 + j] = lv;
  }
}

// split 8 consecutive floats into hi/lo bf16x8 fragments
__device__ __forceinline__ void cvt_split8(const float* __restrict__ p,
                                           bf16x8& h, bf16x8& l) {
  float4 a = *(const float4*)p;
  float4 b = *(const float4*)(p + 4);
#define CVS(e, vv) { __bf16 hh = (__bf16)(vv); h[e] = hh; l[e] = (__bf16)((vv) - (float)hh); }
  CVS(0, a.x) CVS(1, a.y) CVS(2, a.z) CVS(3, a.w)
  CVS(4, b.x) CVS(5, b.y) CVS(6, b.z) CVS(7, b.w)
#undef CVS
}

// ---------------- AB: x-DFT + y-DFT, all MFMA ----------------
// grid 1024 (bi), block 256 (4 waves).
__global__ __launch_bounds__(256, 2) void k_AB(const float* __restrict__ x,
                                               const float* __restrict__ ws,
                                               float2* __restrict__ X2) {
  __shared__ __bf16 AsH[16384];   // As in B-frag layout, hi
  __shared__ __bf16 AsL[16384];   // lo
  const __bf16* frA = (const __bf16*)(ws + T_FA);
  const __bf16* fbc = (const __bf16*)(ws + T_FBC);
  const __bf16* fbs = (const __bf16*)(ws + T_FBS);
  const int t = threadIdx.x, bi = blockIdx.x;
  const int l = t & 63, wv = t >> 6;
  const int lr = l & 15, lk = l >> 4;

  // ---- A phase: As[256 h][64 c] = x · TwX (wave wv: rows wv*64..+63) ----
  f32x4 acc[4][4];
#pragma unroll
  for (int m = 0; m < 4; ++m)
#pragma unroll
    for (int n = 0; n < 4; ++n) acc[m][n] = (f32x4){0.f, 0.f, 0.f, 0.f};
  const float* xb = x + (size_t)bi * 65536 + (size_t)(wv * 64 + lr) * 256 + lk * 8;
  for (int kc = 0; kc < 8; ++kc) {
    bf16x8 ah[4], al[4];
#pragma unroll
    for (int ms = 0; ms < 4; ++ms)
      cvt_split8(xb + ms * 16 * 256 + kc * 32, ah[ms], al[ms]);
    bf16x8 bh[4], bl[4];
#pragma unroll
    for (int ns = 0; ns < 4; ++ns) {
      int fo = ((kc * 4 + ns) * 64 + l) * 8;
      bh[ns] = *(const bf16x8*)(frA + fo);
      bl[ns] = *(const bf16x8*)(frA + 16384 + fo);
    }
#pragma unroll
    for (int ms = 0; ms < 4; ++ms)
#pragma unroll
      for (int ns = 0; ns < 4; ++ns) {
        acc[ms][ns] = __builtin_amdgcn_mfma_f32_16x16x32_bf16(ah[ms], bh[ns], acc[ms][ns], 0, 0, 0);
        acc[ms][ns] = __builtin_amdgcn_mfma_f32_16x16x32_bf16(al[ms], bh[ns], acc[ms][ns], 0, 0, 0);
        acc[ms][ns] = __builtin_amdgcn_mfma_f32_16x16x32_bf16(ah[ms], bl[ns], acc[ms][ns], 0, 0, 0);
      }
  }
  // ---- scatter acc -> LDS in B-frag layout (h = K dim) ----
#pragma unroll
  for (int ms = 0; ms < 4; ++ms)
#pragma unroll
    for (int ns = 0; ns < 4; ++ns)
#pragma unroll
      for (int r = 0; r < 4; ++r) {
        float v = acc[ms][ns][r];
        __bf16 hv = (__bf16)v;
        __bf16 lv = (__bf16)(v - (float)hv);
        int kcB = wv * 2 + (ms >> 1);
        int koff = (ms & 1) * 16 + lk * 4 + r;        // h & 31
        int lp = ((koff >> 3) << 4) + lr;
        int idx = ((kcB * 4 + ns) * 64 + lp) * 8 + (koff & 7);
        AsH[idx] = hv; AsL[idx] = lv;
      }
  __syncthreads();

  // ---- B phase: CyA/SyA [64 m][64 c] (wave wv: m-sub wv) ----
  f32x4 cyA[4], syA[4];
#pragma unroll
  for (int n = 0; n < 4; ++n) { cyA[n] = (f32x4){0.f,0.f,0.f,0.f}; syA[n] = (f32x4){0.f,0.f,0.f,0.f}; }
  for (int kc = 0; kc < 8; ++kc) {
    bf16x8 Bh[4], Bl[4];
#pragma unroll
    for (int ns = 0; ns < 4; ++ns) {
      int fo = ((kc * 4 + ns) * 64 + l) * 8;
      Bh[ns] = *(const bf16x8*)(AsH + fo);
      Bl[ns] = *(const bf16x8*)(AsL + fo);
    }
    int ao = ((kc * 4 + wv) * 64 + l) * 8;
    bf16x8 cyh = *(const bf16x8*)(fbc + ao);
    bf16x8 cyl = *(const bf16x8*)(fbc + 16384 + ao);
    bf16x8 syh = *(const bf16x8*)(fbs + ao);
    bf16x8 syl = *(const bf16x8*)(fbs + 16384 + ao);
#pragma unroll
    for (int ns = 0; ns < 4; ++ns) {
      cyA[ns] = __builtin_amdgcn_mfma_f32_16x16x32_bf16(cyh, Bh[ns], cyA[ns], 0, 0, 0);
      cyA[ns] = __builtin_amdgcn_mfma_f32_16x16x32_bf16(cyl, Bh[ns], cyA[ns], 0, 0, 0);
      cyA[ns] = __builtin_amdgcn_mfma_f32_16x16x32_bf16(cyh, Bl[ns], cyA[ns], 0, 0, 0);
      syA[ns] = __builtin_amdgcn_mfma_f32_16x16x32_bf16(syh, Bh[ns], syA[ns], 0, 0, 0);
      syA[ns] = __builtin_amdgcn_mfma_f32_16x16x32_bf16(syl, Bh[ns], syA[ns], 0, 0, 0);
      syA[ns] = __builtin_amdgcn_mfma_f32_16x16x32_bf16(syh, Bl[ns], syA[ns], 0, 0, 0);
    }
  }
  // ---- combine halves and store X2 ----
  // X2re = CyA[:,kx] + SyA[:,kx+32] ; X2im = CyA[:,kx+32] - SyA[:,kx]
#pragma unroll
  for (int ns = 0; ns < 2; ++ns)
#pragma unroll
    for (int r = 0; r < 4; ++r) {
      int m = wv * 16 + lk * 4 + r;
      int kx = ns * 16 + lr;
      float re = cyA[ns][r] + syA[ns + 2][r];
      float im = cyA[ns + 2][r] - syA[ns][r];
      X2[(size_t)bi * 2048 + m * 32 + kx] = make_float2(re, im);
    }
}

// ---------------- C: channel mix (one block per mode, XCD-chunked) ----------------
__global__ __launch_bounds__(256, 4) void k_C(const float2* __restrict__ X2,
                                              const float* __restrict__ wpr,
                                              const float* __restrict__ wpi,
                                              const float* __restrict__ wnr,
                                              const float* __restrict__ wni,
                                              float2* __restrict__ Cc) {
  __shared__ float2 Xs[16][64];    // [b][i]
  __shared__ float2 Wsh[64][64];   // [i][o]
  const int t = threadIdx.x;
  const int bid = blockIdx.x;
  const int mode = (bid & 7) * 256 + (bid >> 3);   // bijective XCD-chunked map
  const float* wr; const float* wi; int wm;
  if (mode < 1024) { wr = wpr; wi = wpi; wm = mode; }
  else             { wr = wnr; wi = wni; wm = mode - 1024; }

  float2 xv[4];
#pragma unroll
  for (int j = 0; j < 4; ++j) {
    int bi = t + 256 * j;
    xv[j] = X2[(size_t)bi * 2048 + mode];
  }
  float wre[16], wim[16];
#pragma unroll
  for (int k = 0; k < 16; ++k) {
    int io = t + 256 * k;
    size_t a = (size_t)io * 1024 + wm;
    wre[k] = wr[a];
    wim[k] = wi[a];
  }
#pragma unroll
  for (int j = 0; j < 4; ++j) {
    int bi = t + 256 * j;
    Xs[bi >> 6][bi & 63] = xv[j];
  }
#pragma unroll
  for (int k = 0; k < 16; ++k) {
    int io = t + 256 * k;
    Wsh[io >> 6][io & 63] = make_float2(wre[k], wim[k]);
  }
  __syncthreads();

  const int o = t & 63, bg = t >> 6;
  float accr[4] = {0.f, 0.f, 0.f, 0.f};
  float acci[4] = {0.f, 0.f, 0.f, 0.f};
#pragma unroll 4
  for (int i = 0; i < 64; ++i) {
    float2 w = Wsh[i][o];
    float2 x0 = Xs[bg * 4 + 0][i];
    float2 x1 = Xs[bg * 4 + 1][i];
    float2 x2 = Xs[bg * 4 + 2][i];
    float2 x3 = Xs[bg * 4 + 3][i];
    accr[0] = fmaf(x0.x, w.x, fmaf(-x0.y, w.y, accr[0]));
    acci[0] = fmaf(x0.x, w.y, fmaf( x0.y, w.x, acci[0]));
    accr[1] = fmaf(x1.x, w.x, fmaf(-x1.y, w.y, accr[1]));
    acci[1] = fmaf(x1.x, w.y, fmaf( x1.y, w.x, acci[1]));
    accr[2] = fmaf(x2.x, w.x, fmaf(-x2.y, w.y, accr[2]));
    acci[2] = fmaf(x2.x, w.y, fmaf( x2.y, w.x, acci[2]));
    accr[3] = fmaf(x3.x, w.x, fmaf(-x3.y, w.y, accr[3]));
    acci[3] = fmaf(x3.x, w.y, fmaf( x3.y, w.x, acci[3]));
  }

  const float scale = (((mode & 31) == 0) ? 1.f : 2.f) * (1.f / 65536.f);
#pragma unroll
  for (int j = 0; j < 4; ++j) {
    int b = bg * 4 + j;
    Cc[(size_t)(b * 64 + o) * 2048 + mode] =
        make_float2(accr[j] * scale, acci[j] * scale);
  }
}

// ---------------- DE: inverse-y + inverse-x + Re(), all MFMA ----------------
// grid 1024 (bo), block 256 (4 waves).
__global__ __launch_bounds__(256, 2) void k_DE(const float2* __restrict__ Cc,
                                               const float* __restrict__ ws,
                                               float* __restrict__ out) {
  __shared__ __bf16 CH[4096], CL[4096];     // Cstack[128][32] B-frags
  __shared__ __bf16 EH[16384], EL[16384];   // Y in E's A-frag layout
  const __bf16* fdr = (const __bf16*)(ws + T_FDR);
  const __bf16* fdn = (const __bf16*)(ws + T_FDN);
  const __bf16* frE = (const __bf16*)(ws + T_FE);
  const int t = threadIdx.x, bo = blockIdx.x;
  const int l = t & 63, wv = t >> 6;
  const int lr = l & 15, lk = l >> 4;

  // ---- stage Cc -> B-frag LDS (Cstack: k<64 = Cr[m], k>=64 = Ci[m]) ----
  const float2* Cp = Cc + (size_t)bo * 2048;
#pragma unroll
  for (int jj = 0; jj < 8; ++jj) {
    int j = t + 256 * jj;
    float2 v = Cp[j];
    int m = j >> 5, kx = j & 31;
    int ns = kx >> 4;
    int lp = ((m & 31) >> 3) * 16 + (kx & 15);
    int e = m & 7;
    int idxR = (((m >> 5) * 2 + ns) * 64 + lp) * 8 + e;
    int idxI = ((((m >> 5) + 2) * 2 + ns) * 64 + lp) * 8 + e;
    __bf16 h1 = (__bf16)v.x; CH[idxR] = h1; CL[idxR] = (__bf16)(v.x - (float)h1);
    __bf16 h2 = (__bf16)v.y; CH[idxI] = h2; CL[idxI] = (__bf16)(v.y - (float)h2);
  }
  __syncthreads();

  // ---- D phase: Y[h][c]: c<32 = Re (Tre), c>=32 = -Im (Tnim); wave wv: h rows wv*64..+63 ----
  f32x4 dr[4][2], dn[4][2];
#pragma unroll
  for (int ms = 0; ms < 4; ++ms)
#pragma unroll
    for (int ns = 0; ns < 2; ++ns) { dr[ms][ns] = (f32x4){0.f,0.f,0.f,0.f}; dn[ms][ns] = (f32x4){0.f,0.f,0.f,0.f}; }
  for (int kc = 0; kc < 4; ++kc) {
    bf16x8 Bh[2], Bl[2];
#pragma unroll
    for (int ns = 0; ns < 2; ++ns) {
      int fo = ((kc * 2 + ns) * 64 + l) * 8;
      Bh[ns] = *(const bf16x8*)(CH + fo);
      Bl[ns] = *(const bf16x8*)(CL + fo);
    }
#pragma unroll
    for (int ms = 0; ms < 4; ++ms) {
      int ao = (((wv * 4 + ms) * 4 + kc) * 64 + l) * 8;
      bf16x8 rh = *(const bf16x8*)(fdr + ao);
      bf16x8 rl = *(const bf16x8*)(fdr + 32768 + ao);
      bf16x8 nh = *(const bf16x8*)(fdn + ao);
      bf16x8 nl = *(const bf16x8*)(fdn + 32768 + ao);
#pragma unroll
      for (int ns = 0; ns < 2; ++ns) {
        dr[ms][ns] = __builtin_amdgcn_mfma_f32_16x16x32_bf16(rh, Bh[ns], dr[ms][ns], 0, 0, 0);
        dr[ms][ns] = __builtin_amdgcn_mfma_f32_16x16x32_bf16(rl, Bh[ns], dr[ms][ns], 0, 0, 0);
        dr[ms][ns] = __builtin_amdgcn_mfma_f32_16x16x32_bf16(rh, Bl[ns], dr[ms][ns], 0, 0, 0);
        dn[ms][ns] = __builtin_amdgcn_mfma_f32_16x16x32_bf16(nh, Bh[ns], dn[ms][ns], 0, 0, 0);
        dn[ms][ns] = __builtin_amdgcn_mfma_f32_16x16x32_bf16(nl, Bh[ns], dn[ms][ns], 0, 0, 0);
        dn[ms][ns] = __builtin_amdgcn_mfma_f32_16x16x32_bf16(nh, Bl[ns], dn[ms][ns], 0, 0, 0);
      }
    }
  }
  // ---- scatter Y -> E's A-frag layout (wave-local rows) ----
#pragma unroll
  for (int ms = 0; ms < 4; ++ms)
#pragma unroll
    for (int ns = 0; ns < 2; ++ns)
#pragma unroll
      for (int r = 0; r < 4; ++r) {
        int hloc = lk * 4 + r;                  // h & 15
        int cq = ns * 2 + (lr >> 3);            // (c&31)>>3
        {
          float v = dr[ms][ns][r];              // c = ns*16+lr (kcE = 0)
          __bf16 hv = (__bf16)v;
          int idx = (((wv * 4 + ms) * 2 + 0) * 64 + cq * 16 + hloc) * 8 + (lr & 7);
          EH[idx] = hv; EL[idx] = (__bf16)(v - (float)hv);
        }
        {
          float v = dn[ms][ns][r];              // c = 32+ns*16+lr (kcE = 1)
          __bf16 hv = (__bf16)v;
          int idx = (((wv * 4 + ms) * 2 + 1) * 64 + cq * 16 + hloc) * 8 + (lr & 7);
          EH[idx] = hv; EL[idx] = (__bf16)(v - (float)hv);
        }
      }
  __syncthreads();

  // ---- E phase: out[256][256] = Y · TwXT (wave wv: rows wv*64..+63) ----
  bf16x8 ah[4][2], al[4][2];
#pragma unroll
  for (int ms = 0; ms < 4; ++ms)
#pragma unroll
    for (int kc = 0; kc < 2; ++kc) {
      int fo = (((wv * 4 + ms) * 2 + kc) * 64 + l) * 8;
      ah[ms][kc] = *(const bf16x8*)(EH + fo);
      al[ms][kc] = *(const bf16x8*)(EL + fo);
    }
  float* ob = out + (size_t)bo * 65536;
  for (int cb = 0; cb < 4; ++cb) {
    f32x4 eacc[4][4];
#pragma unroll
    for (int m = 0; m < 4; ++m)
#pragma unroll
      for (int n = 0; n < 4; ++n) eacc[m][n] = (f32x4){0.f, 0.f, 0.f, 0.f};
#pragma unroll
    for (int kc = 0; kc < 2; ++kc) {
      bf16x8 bh[4], bl[4];
#pragma unroll
      for (int ns = 0; ns < 4; ++ns) {
        int fo = ((kc * 16 + cb * 4 + ns) * 64 + l) * 8;
        bh[ns] = *(const bf16x8*)(frE + fo);
        bl[ns] = *(const bf16x8*)(frE + 16384 + fo);
      }
#pragma unroll
      for (int ms = 0; ms < 4; ++ms)
#pragma unroll
        for (int ns = 0; ns < 4; ++ns) {
          eacc[ms][ns] = __builtin_amdgcn_mfma_f32_16x16x32_bf16(ah[ms][kc], bh[ns], eacc[ms][ns], 0, 0, 0);
          eacc[ms][ns] = __builtin_amdgcn_mfma_f32_16x16x32_bf16(al[ms][kc], bh[ns], eacc[ms][ns], 0, 0, 0);
          eacc[ms][ns] = __builtin_amdgcn_mfma_f32_16x16x32_bf16(ah[ms][kc], bl[ns], eacc[ms][ns], 0, 0, 0);
        }
    }
#pragma unroll
    for (int ms = 0; ms < 4; ++ms)
#pragma unroll
      for (int ns = 0; ns < 4; ++ns) {
        int col = cb * 64 + ns * 16 + lr;
        int row0 = wv * 64 + ms * 16 + lk * 4;
#pragma unroll
        for (int r = 0; r < 4; ++r)
          ob[(size_t)(row0 + r) * 256 + col] = eacc[ms][ns][r];
      }
  }
}

extern "C" void kernel_launch(void* const* d_in, const int* in_sizes, int n_in,
                              void* d_out, int out_size, void* d_ws, size_t ws_size,
                              hipStream_t stream) {
  (void)in_sizes; (void)n_in; (void)out_size; (void)ws_size;
  const float* x   = (const float*)d_in[0];
  const float* wpr = (const float*)d_in[1];
  const float* wpi = (const float*)d_in[2];
  const float* wnr = (const float*)d_in[3];
  const float* wni = (const float*)d_in[4];
  float* out = (float*)d_out;
  float* ws  = (float*)d_ws;

  float2* X2 = (float2*)(ws + T_X2);   // [1024][2048] float2
  float2* Cc = (float2*)(ws + T_CC);   // [1024][2048] float2

  k_prep<<<512, 256, 0, stream>>>(ws);
  k_AB<<<1024, 256, 0, stream>>>(x, ws, X2);
  k_C<<<2048, 256, 0, stream>>>(X2, wpr, wpi, wnr, wni, Cc);
  k_DE<<<1024, 256, 0, stream>>>(Cc, ws, out);
}

// Round 8
// 219.485 us; speedup vs baseline: 2.8004x; 1.3333x over previous
//
#include <hip/hip_runtime.h>
#include <math.h>

#define PI_F 3.14159265358979323846f

// x:[16][64][256][256] f32, weights ×4:[64][64][32][32] f32, out:[16][64][256][256] f32
// modes: ky m=0..63 -> ky = m (m<32) else m+192 ; kx = 0..31
//
// Fully-MFMA pipeline (X2/Cc + frag tables in d_ws):
//   AB: per bi: x-DFT MFMA -> LDS B-frags (packed b64 scatter) -> y-DFT MFMA -> X2
//   C : coalesced-mode channel mix (lanes span modes; W read once, coalesced)
//   DE: Cc -> A-frags; TRANSPOSED inv-y MFMA (Yt = Cstack^T · T) -> packed b64
//       scatter into E A-frags (wave-local) -> inv-x MFMA -> out
//
// Frag conventions (R6/R7-validated):
//   A-frag: row = lane&15, k = (lane>>4)*8 + e
//   B-frag: col = lane&15, k = (lane>>4)*8 + e
//   C/D   : col = lane&15, row = (lane>>4)*4 + reg

static constexpr int T_FA  = 0;         // x-DFT B-frag table  hi|lo (32768 bf16)
static constexpr int T_FE  = 16384;     // inv-x  B-frag table hi|lo (32768 bf16)
static constexpr int T_FBC = 32768;     // y-DFT Cy A-frag     hi|lo (32768 bf16)
static constexpr int T_FBS = 49152;     // y-DFT Sy A-frag     hi|lo (32768 bf16)
static constexpr int T_FD1 = 65536;     // inv-y T1 B-frag     hi|lo (65536 bf16)
static constexpr int T_FD2 = 98304;     // inv-y T2 B-frag     hi|lo (65536 bf16)
static constexpr int T_X2  = 131072;                 // [1024][2048] float2
static constexpr int T_CC  = 131072 + 4194304;       // [1024][2048] float2

typedef __attribute__((ext_vector_type(8))) __bf16 bf16x8;
typedef __attribute__((ext_vector_type(4))) float f32x4;

union B4 { __bf16 b[4]; uint2 u; };

// ---------------- fragment tables ----------------
__global__ __launch_bounds__(256) void k_prep(float* __restrict__ ws) {
  int idx = blockIdx.x * 256 + threadIdx.x;
  const float C = 2.0f * PI_F / 256.0f;
  if (idx < 16384) {
    // FA: B[n=col][k=w]; frag q = kc*4+ns (kc<8)
    int j = idx;
    int e = j & 7, l = (j >> 3) & 63, q = j >> 9;
    int ns = q & 3, kc = q >> 2;
    int w = kc * 32 + ((l >> 4) & 3) * 8 + e;
    int col = ns * 16 + (l & 15);
    int kxi = col & 31;
    float ang = C * (float)((kxi * w) & 255);
    float v = (col < 32) ? cosf(ang) : -sinf(ang);
    __bf16 hv = (__bf16)v;
    __bf16 lv = (__bf16)(v - (float)hv);
    __bf16* fr = (__bf16*)(ws + T_FA);
    fr[j] = hv; fr[16384 + j] = lv;
  } else if (idx < 32768) {
    // FE: B[n=w][k=c]; frag q = kc*16+wblk (kc<2)
    int j = idx - 16384;
    int e = j & 7, l = (j >> 3) & 63, q = j >> 9;
    int wb = q & 15, kc = q >> 4;
    int c = kc * 32 + ((l >> 4) & 3) * 8 + e;
    int w = wb * 16 + (l & 15);
    int kxi = (c < 32) ? c : (c - 32);
    float ang = C * (float)((kxi * w) & 255);
    float v = (c < 32) ? cosf(ang) : sinf(ang);
    __bf16 hv = (__bf16)v;
    __bf16 lv = (__bf16)(v - (float)hv);
    __bf16* fr = (__bf16*)(ws + T_FE);
    fr[j] = hv; fr[16384 + j] = lv;
  } else if (idx < 65536) {
    // FBC/FBS: A[row=m][k=h]; frag q = kc*4+ms4 (kc<8)
    int base = (idx < 49152) ? 32768 : 49152;
    int j = idx - base;
    int e = j & 7, l = (j >> 3) & 63, q = j >> 9;
    int ms4 = q & 3, kc = q >> 2;
    int m = ms4 * 16 + (l & 15);
    int h = kc * 32 + ((l >> 4) & 3) * 8 + e;
    int ky = (m < 32) ? m : (m + 192);
    float ang = C * (float)((ky * h) & 255);
    float v = (idx < 49152) ? cosf(ang) : sinf(ang);
    __bf16 hv = (__bf16)v;
    __bf16 lv = (__bf16)(v - (float)hv);
    __bf16* fr = (__bf16*)(ws + base);
    fr[j] = hv; fr[16384 + j] = lv;
  } else if (idx < 131072) {
    // FD1/FD2: B[k = m-stack 128][col = h]; frag f = (wv*4+kc)*4+nsH
    int base = (idx < 98304) ? T_FD1 : T_FD2;
    int j = idx - base;
    int e = j & 7, l = (j >> 3) & 63, f = j >> 9;     // f 0..63
    int nsH = f & 3, kc = (f >> 2) & 3, wv = f >> 4;
    int h = wv * 64 + nsH * 16 + (l & 15);
    int k = kc * 32 + ((l >> 4) & 3) * 8 + e;
    int m = (k < 64) ? k : (k - 64);
    int ky = (m < 32) ? m : (m + 192);
    float ang = C * (float)((ky * h) & 255);
    float cv = cosf(ang), sv = sinf(ang);
    float v;
    if (idx < 98304) v = (k < 64) ? cv : -sv;    // T1:  cy | -sy  -> Yre
    else             v = (k < 64) ? -sv : -cv;   // T2: -sy | -cy  -> -Yim
    __bf16 hv = (__bf16)v;
    __bf16 lv = (__bf16)(v - (float)hv);
    __bf16* fr = (__bf16*)(ws + base);
    fr[j] = hv; fr[32768 + j] = lv;
  }
}

// split 8 consecutive floats into hi/lo bf16x8 fragments
__device__ __forceinline__ void cvt_split8(const float* __restrict__ p,
                                           bf16x8& h, bf16x8& l) {
  float4 a = *(const float4*)p;
  float4 b = *(const float4*)(p + 4);
#define CVS(e, vv) { __bf16 hh = (__bf16)(vv); h[e] = hh; l[e] = (__bf16)((vv) - (float)hh); }
  CVS(0, a.x) CVS(1, a.y) CVS(2, a.z) CVS(3, a.w)
  CVS(4, b.x) CVS(5, b.y) CVS(6, b.z) CVS(7, b.w)
#undef CVS
}

// ---------------- AB: x-DFT + y-DFT, all MFMA ----------------
__global__ __launch_bounds__(256, 2) void k_AB(const float* __restrict__ x,
                                               const float* __restrict__ ws,
                                               float2* __restrict__ X2) {
  __shared__ __bf16 AsH[16384];
  __shared__ __bf16 AsL[16384];
  const __bf16* frA = (const __bf16*)(ws + T_FA);
  const __bf16* fbc = (const __bf16*)(ws + T_FBC);
  const __bf16* fbs = (const __bf16*)(ws + T_FBS);
  const int t = threadIdx.x, bi = blockIdx.x;
  const int l = t & 63, wv = t >> 6;
  const int lr = l & 15, lk = l >> 4;

  // ---- A phase ----
  f32x4 acc[4][4];
#pragma unroll
  for (int m = 0; m < 4; ++m)
#pragma unroll
    for (int n = 0; n < 4; ++n) acc[m][n] = (f32x4){0.f, 0.f, 0.f, 0.f};
  const float* xb = x + (size_t)bi * 65536 + (size_t)(wv * 64 + lr) * 256 + lk * 8;
  for (int kc = 0; kc < 8; ++kc) {
    bf16x8 ah[4], al[4];
#pragma unroll
    for (int ms = 0; ms < 4; ++ms)
      cvt_split8(xb + ms * 16 * 256 + kc * 32, ah[ms], al[ms]);
    bf16x8 bh[4], bl[4];
#pragma unroll
    for (int ns = 0; ns < 4; ++ns) {
      int fo = ((kc * 4 + ns) * 64 + l) * 8;
      bh[ns] = *(const bf16x8*)(frA + fo);
      bl[ns] = *(const bf16x8*)(frA + 16384 + fo);
    }
#pragma unroll
    for (int ms = 0; ms < 4; ++ms)
#pragma unroll
      for (int ns = 0; ns < 4; ++ns) {
        acc[ms][ns] = __builtin_amdgcn_mfma_f32_16x16x32_bf16(ah[ms], bh[ns], acc[ms][ns], 0, 0, 0);
        acc[ms][ns] = __builtin_amdgcn_mfma_f32_16x16x32_bf16(al[ms], bh[ns], acc[ms][ns], 0, 0, 0);
        acc[ms][ns] = __builtin_amdgcn_mfma_f32_16x16x32_bf16(ah[ms], bl[ns], acc[ms][ns], 0, 0, 0);
      }
  }
  // ---- packed scatter -> LDS B-frags ----
#pragma unroll
  for (int ms = 0; ms < 4; ++ms)
#pragma unroll
    for (int ns = 0; ns < 4; ++ns) {
      int kcB = wv * 2 + (ms >> 1);
      int quad = (ms & 1) * 2 + (lk >> 1);
      int base = ((kcB * 4 + ns) * 64 + quad * 16 + lr) * 8 + (lk & 1) * 4;
      B4 ph, pl;
#pragma unroll
      for (int r = 0; r < 4; ++r) {
        float v = acc[ms][ns][r];
        __bf16 hv = (__bf16)v;
        ph.b[r] = hv; pl.b[r] = (__bf16)(v - (float)hv);
      }
      *(uint2*)&AsH[base] = ph.u;
      *(uint2*)&AsL[base] = pl.u;
    }
  __syncthreads();

  // ---- B phase ----
  f32x4 cyA[4], syA[4];
#pragma unroll
  for (int n = 0; n < 4; ++n) { cyA[n] = (f32x4){0.f,0.f,0.f,0.f}; syA[n] = (f32x4){0.f,0.f,0.f,0.f}; }
  for (int kc = 0; kc < 8; ++kc) {
    bf16x8 Bh[4], Bl[4];
#pragma unroll
    for (int ns = 0; ns < 4; ++ns) {
      int fo = ((kc * 4 + ns) * 64 + l) * 8;
      Bh[ns] = *(const bf16x8*)(AsH + fo);
      Bl[ns] = *(const bf16x8*)(AsL + fo);
    }
    int ao = ((kc * 4 + wv) * 64 + l) * 8;
    bf16x8 cyh = *(const bf16x8*)(fbc + ao);
    bf16x8 cyl = *(const bf16x8*)(fbc + 16384 + ao);
    bf16x8 syh = *(const bf16x8*)(fbs + ao);
    bf16x8 syl = *(const bf16x8*)(fbs + 16384 + ao);
#pragma unroll
    for (int ns = 0; ns < 4; ++ns) {
      cyA[ns] = __builtin_amdgcn_mfma_f32_16x16x32_bf16(cyh, Bh[ns], cyA[ns], 0, 0, 0);
      cyA[ns] = __builtin_amdgcn_mfma_f32_16x16x32_bf16(cyl, Bh[ns], cyA[ns], 0, 0, 0);
      cyA[ns] = __builtin_amdgcn_mfma_f32_16x16x32_bf16(cyh, Bl[ns], cyA[ns], 0, 0, 0);
      syA[ns] = __builtin_amdgcn_mfma_f32_16x16x32_bf16(syh, Bh[ns], syA[ns], 0, 0, 0);
      syA[ns] = __builtin_amdgcn_mfma_f32_16x16x32_bf16(syl, Bh[ns], syA[ns], 0, 0, 0);
      syA[ns] = __builtin_amdgcn_mfma_f32_16x16x32_bf16(syh, Bl[ns], syA[ns], 0, 0, 0);
    }
  }
#pragma unroll
  for (int ns = 0; ns < 2; ++ns)
#pragma unroll
    for (int r = 0; r < 4; ++r) {
      int m = wv * 16 + lk * 4 + r;
      int kx = ns * 16 + lr;
      float re = cyA[ns][r] + syA[ns + 2][r];
      float im = cyA[ns + 2][r] - syA[ns][r];
      X2[(size_t)bi * 2048 + m * 32 + kx] = make_float2(re, im);
    }
}

// ---------------- C: channel mix, coalesced-mode ----------------
// grid 1024: mc = bid&63 (32-mode chunk), ot = bid>>6 (4-o tile).
// bid%8 = mc%8 -> same-mc blocks share an XCD L2 (X2 slice reuse x16).
// W read exactly once, fully coalesced (mode-minor layout), staged 4 i's deep.
__global__ __launch_bounds__(256, 4) void k_C(const float2* __restrict__ X2,
                                              const float* __restrict__ wpr,
                                              const float* __restrict__ wpi,
                                              const float* __restrict__ wnr,
                                              const float* __restrict__ wni,
                                              float2* __restrict__ Cc) {
  __shared__ float2 Xs[2][16][32];     // [buf][b][md]
  __shared__ float2 Ws[2][4][4][32];   // [buf][iS][og][md]
  const int t = threadIdx.x;
  const int mc = blockIdx.x & 63, ot = blockIdx.x >> 6;
  const int mode0 = mc * 32;
  const float *wr, *wi; int wm0;
  if (mode0 < 1024) { wr = wpr; wi = wpi; wm0 = mode0; }
  else              { wr = wnr; wi = wni; wm0 = mode0 - 1024; }
  // compute mapping: thread owns 4 b x 2 o at one mode
  const int md = t & 31, og2 = (t >> 5) & 1, bq = t >> 6;
  // X stage mapping
  const int bS = t >> 4, c2 = (t & 15) * 2;
  // W stage mapping (2 float2 per thread)
  const int e0 = t * 2;
  const int wiS = e0 >> 7, wog = (e0 >> 5) & 3, wmd = e0 & 31;

  float ar[4][2], ai[4][2];
#pragma unroll
  for (int b = 0; b < 4; ++b) { ar[b][0]=0.f; ar[b][1]=0.f; ai[b][0]=0.f; ai[b][1]=0.f; }

  // prologue: stage X(i=0) buf0, W(iblk=0) buf0
  *(float4*)&Xs[0][bS][c2] =
      *(const float4*)&X2[((size_t)(bS * 64 + 0)) * 2048 + mode0 + c2];
  {
    size_t wa = ((size_t)(wiS * 64) + ot * 4 + wog) * 1024 + wm0 + wmd;
    float2 r2 = *(const float2*)&wr[wa];
    float2 i2 = *(const float2*)&wi[wa];
    Ws[0][wiS][wog][wmd]     = make_float2(r2.x, i2.x);
    Ws[0][wiS][wog][wmd + 1] = make_float2(r2.y, i2.y);
  }
  __syncthreads();

  for (int i = 0; i < 64; ++i) {
    const int cur = i & 1, wcur = (i >> 2) & 1;
    if (i < 63)
      *(float4*)&Xs[cur ^ 1][bS][c2] =
          *(const float4*)&X2[((size_t)(bS * 64 + i + 1)) * 2048 + mode0 + c2];
    if ((i & 3) == 0 && i < 60) {
      size_t wa = ((size_t)((i + 4 + wiS) * 64) + ot * 4 + wog) * 1024 + wm0 + wmd;
      float2 r2 = *(const float2*)&wr[wa];
      float2 i2 = *(const float2*)&wi[wa];
      Ws[wcur ^ 1][wiS][wog][wmd]     = make_float2(r2.x, i2.x);
      Ws[wcur ^ 1][wiS][wog][wmd + 1] = make_float2(r2.y, i2.y);
    }
    float2 w0 = Ws[wcur][i & 3][og2 * 2 + 0][md];
    float2 w1 = Ws[wcur][i & 3][og2 * 2 + 1][md];
#pragma unroll
    for (int b = 0; b < 4; ++b) {
      float2 xv = Xs[cur][bq * 4 + b][md];
      ar[b][0] = fmaf(xv.x, w0.x, fmaf(-xv.y, w0.y, ar[b][0]));
      ai[b][0] = fmaf(xv.x, w0.y, fmaf( xv.y, w0.x, ai[b][0]));
      ar[b][1] = fmaf(xv.x, w1.x, fmaf(-xv.y, w1.y, ar[b][1]));
      ai[b][1] = fmaf(xv.x, w1.y, fmaf( xv.y, w1.x, ai[b][1]));
    }
    __syncthreads();
  }

  const float scale = ((md == 0) ? 1.f : 2.f) * (1.f / 65536.f);
#pragma unroll
  for (int b = 0; b < 4; ++b)
#pragma unroll
    for (int o2 = 0; o2 < 2; ++o2)
      Cc[((size_t)((bq * 4 + b) * 64 + ot * 4 + og2 * 2 + o2)) * 2048 + mode0 + md] =
          make_float2(ar[b][o2] * scale, ai[b][o2] * scale);
}

// ---------------- DE: transposed inv-y + inv-x + Re(), all MFMA ----------------
__global__ __launch_bounds__(256, 2) void k_DE(const float2* __restrict__ Cc,
                                               const float* __restrict__ ws,
                                               float* __restrict__ out) {
  __shared__ __bf16 CH[4096], CL[4096];     // Cstack^T A-frags [msK2][kc4][64][8]
  __shared__ __bf16 EH[16384], EL[16384];   // Y in E's A-frag layout
  const __bf16* fd1 = (const __bf16*)(ws + T_FD1);
  const __bf16* fd2 = (const __bf16*)(ws + T_FD2);
  const __bf16* frE = (const __bf16*)(ws + T_FE);
  const int t = threadIdx.x, bo = blockIdx.x;
  const int l = t & 63, wv = t >> 6;
  const int lr = l & 15, lk = l >> 4;

  // ---- stage Cc -> A-frag LDS: row = kx, k = m (Cr) | m+64 (Ci) ----
  const float2* Cp = Cc + (size_t)bo * 2048;
#pragma unroll
  for (int jj = 0; jj < 8; ++jj) {
    int j = t + 256 * jj;
    float2 v = Cp[j];
    int m = j >> 5, kx = j & 31;
    int msK = kx >> 4, lA = ((m >> 3) & 3) * 16 + (kx & 15);
    int e = m & 7, kcR = m >> 5;
    int idxR = ((msK * 4 + kcR) * 64 + lA) * 8 + e;
    int idxI = ((msK * 4 + kcR + 2) * 64 + lA) * 8 + e;
    __bf16 h1 = (__bf16)v.x; CH[idxR] = h1; CL[idxR] = (__bf16)(v.x - (float)h1);
    __bf16 h2 = (__bf16)v.y; CH[idxI] = h2; CL[idxI] = (__bf16)(v.y - (float)h2);
  }
  __syncthreads();

  // ---- D phase (transposed): z1 = Yre^T, z2 = (-Yim)^T ; rows = kx, cols = h ----
  f32x4 z1[2][4], z2[2][4];
#pragma unroll
  for (int m = 0; m < 2; ++m)
#pragma unroll
    for (int n = 0; n < 4; ++n) { z1[m][n] = (f32x4){0.f,0.f,0.f,0.f}; z2[m][n] = (f32x4){0.f,0.f,0.f,0.f}; }
  for (int kc = 0; kc < 4; ++kc) {
    bf16x8 ah[2], al[2];
#pragma unroll
    for (int msK = 0; msK < 2; ++msK) {
      int fo = ((msK * 4 + kc) * 64 + l) * 8;
      ah[msK] = *(const bf16x8*)(CH + fo);
      al[msK] = *(const bf16x8*)(CL + fo);
    }
#pragma unroll
    for (int nsH = 0; nsH < 4; ++nsH) {
      int bo_ = (((wv * 4 + kc) * 4 + nsH) * 64 + l) * 8;
      bf16x8 b1h = *(const bf16x8*)(fd1 + bo_);
      bf16x8 b1l = *(const bf16x8*)(fd1 + 32768 + bo_);
      bf16x8 b2h = *(const bf16x8*)(fd2 + bo_);
      bf16x8 b2l = *(const bf16x8*)(fd2 + 32768 + bo_);
#pragma unroll
      for (int msK = 0; msK < 2; ++msK) {
        z1[msK][nsH] = __builtin_amdgcn_mfma_f32_16x16x32_bf16(ah[msK], b1h, z1[msK][nsH], 0, 0, 0);
        z1[msK][nsH] = __builtin_amdgcn_mfma_f32_16x16x32_bf16(al[msK], b1h, z1[msK][nsH], 0, 0, 0);
        z1[msK][nsH] = __builtin_amdgcn_mfma_f32_16x16x32_bf16(ah[msK], b1l, z1[msK][nsH], 0, 0, 0);
        z2[msK][nsH] = __builtin_amdgcn_mfma_f32_16x16x32_bf16(ah[msK], b2h, z2[msK][nsH], 0, 0, 0);
        z2[msK][nsH] = __builtin_amdgcn_mfma_f32_16x16x32_bf16(al[msK], b2h, z2[msK][nsH], 0, 0, 0);
        z2[msK][nsH] = __builtin_amdgcn_mfma_f32_16x16x32_bf16(ah[msK], b2l, z2[msK][nsH], 0, 0, 0);
      }
    }
  }
  // ---- packed scatter -> E A-frags (wave-local) ----
  // value (msK,nsH,r): kx = msK*16+lk*4+r, h_local = nsH*16+lr
  // E idx: (((wv*4+msE)*2+kcE)*64 + lp)*8 + e ; msE=nsH, kcE=0(z1)/1(z2),
  // lp = (msK*2+(lk>>1))*16 + lr, e = (lk&1)*4 + r
#pragma unroll
  for (int msK = 0; msK < 2; ++msK)
#pragma unroll
    for (int nsH = 0; nsH < 4; ++nsH) {
      int lp = (msK * 2 + (lk >> 1)) * 16 + lr;
      int eb = (lk & 1) * 4;
      int base1 = (((wv * 4 + nsH) * 2 + 0) * 64 + lp) * 8 + eb;
      int base2 = (((wv * 4 + nsH) * 2 + 1) * 64 + lp) * 8 + eb;
      B4 p1h, p1l, p2h, p2l;
#pragma unroll
      for (int r = 0; r < 4; ++r) {
        float v1 = z1[msK][nsH][r];
        __bf16 h1 = (__bf16)v1; p1h.b[r] = h1; p1l.b[r] = (__bf16)(v1 - (float)h1);
        float v2 = z2[msK][nsH][r];
        __bf16 h2 = (__bf16)v2; p2h.b[r] = h2; p2l.b[r] = (__bf16)(v2 - (float)h2);
      }
      *(uint2*)&EH[base1] = p1h.u; *(uint2*)&EL[base1] = p1l.u;
      *(uint2*)&EH[base2] = p2h.u; *(uint2*)&EL[base2] = p2l.u;
    }
  __syncthreads();

  // ---- E phase ----
  bf16x8 ah[4][2], al[4][2];
#pragma unroll
  for (int ms = 0; ms < 4; ++ms)
#pragma unroll
    for (int kc = 0; kc < 2; ++kc) {
      int fo = (((wv * 4 + ms) * 2 + kc) * 64 + l) * 8;
      ah[ms][kc] = *(const bf16x8*)(EH + fo);
      al[ms][kc] = *(const bf16x8*)(EL + fo);
    }
  float* ob = out + (size_t)bo * 65536;
  for (int cb = 0; cb < 4; ++cb) {
    f32x4 eacc[4][4];
#pragma unroll
    for (int m = 0; m < 4; ++m)
#pragma unroll
      for (int n = 0; n < 4; ++n) eacc[m][n] = (f32x4){0.f, 0.f, 0.f, 0.f};
#pragma unroll
    for (int kc = 0; kc < 2; ++kc) {
      bf16x8 bh[4], bl[4];
#pragma unroll
      for (int ns = 0; ns < 4; ++ns) {
        int fo = ((kc * 16 + cb * 4 + ns) * 64 + l) * 8;
        bh[ns] = *(const bf16x8*)(frE + fo);
        bl[ns] = *(const bf16x8*)(frE + 16384 + fo);
      }
#pragma unroll
      for (int ms = 0; ms < 4; ++ms)
#pragma unroll
        for (int ns = 0; ns < 4; ++ns) {
          eacc[ms][ns] = __builtin_amdgcn_mfma_f32_16x16x32_bf16(ah[ms][kc], bh[ns], eacc[ms][ns], 0, 0, 0);
          eacc[ms][ns] = __builtin_amdgcn_mfma_f32_16x16x32_bf16(al[ms][kc], bh[ns], eacc[ms][ns], 0, 0, 0);
          eacc[ms][ns] = __builtin_amdgcn_mfma_f32_16x16x32_bf16(ah[ms][kc], bl[ns], eacc[ms][ns], 0, 0, 0);
        }
    }
#pragma unroll
    for (int ms = 0; ms < 4; ++ms)
#pragma unroll
      for (int ns = 0; ns < 4; ++ns) {
        int col = cb * 64 + ns * 16 + lr;
        int row0 = wv * 64 + ms * 16 + lk * 4;
#pragma unroll
        for (int r = 0; r < 4; ++r)
          ob[(size_t)(row0 + r) * 256 + col] = eacc[ms][ns][r];
      }
  }
}

extern "C" void kernel_launch(void* const* d_in, const int* in_sizes, int n_in,
                              void* d_out, int out_size, void* d_ws, size_t ws_size,
                              hipStream_t stream) {
  (void)in_sizes; (void)n_in; (void)out_size; (void)ws_size;
  const float* x   = (const float*)d_in[0];
  const float* wpr = (const float*)d_in[1];
  const float* wpi = (const float*)d_in[2];
  const float* wnr = (const float*)d_in[3];
  const float* wni = (const float*)d_in[4];
  float* out = (float*)d_out;
  float* ws  = (float*)d_ws;

  float2* X2 = (float2*)(ws + T_X2);   // [1024][2048] float2
  float2* Cc = (float2*)(ws + T_CC);   // [1024][2048] float2

  k_prep<<<512, 256, 0, stream>>>(ws);
  k_AB<<<1024, 256, 0, stream>>>(x, ws, X2);
  k_C<<<1024, 256, 0, stream>>>(X2, wpr, wpi, wnr, wni, Cc);
  k_DE<<<1024, 256, 0, stream>>>(Cc, ws, out);
}